// Round 8
// baseline (91.854 us; speedup 1.0000x reference)
//
#include <hip/hip_runtime.h>

typedef _Float16 h2 __attribute__((ext_vector_type(2)));

#define GRID_W 4
#define GRID_H 4
#define NEXP   16
#define HID    256
#define STPB   1024           // sort block threads
#define S      2
#define SAMP   (STPB * S)     // 2048 samples per sort block
#define WPE    1536           // fp16 halves per expert in ws
#define MAXE   48             // max entries per sort block: 16 + 2048/64
#define MTPB   256            // mlp block threads
#define MWAVES (MTPB / 64)

// ---- ws layout (bytes) ----
// [0,       49152): fp16 weights [16][1536] k-major
// [65536,  262144): int4 entries[nsb*48]  (expert, slot_base, cnt, 0)
// [4MB,        ..): int2 slots[nsb*2048 + pad]  {half2(x,y), gid}
#define WSOFF_ENT  65536
#define WSOFF_SLOT (4u << 20)

// ---------------------------------------------------------------------------
// Kernel A: weights fp32 -> fp16, k-major per expert:
// [0,256)=W1 row x, [256,512)=W1 row y, [512,768)=b1, [768..1536)=W2 cols 0,1,2
// ---------------------------------------------------------------------------
__global__ __launch_bounds__(256) void convert_kernel(
    const float* __restrict__ W1, const float* __restrict__ b1,
    const float* __restrict__ W2, _Float16* __restrict__ wsW) {
    int t = blockIdx.x * 256 + threadIdx.x;     // 4096 threads
    int e = t >> 8, k = t & 255;
    _Float16* dst = wsW + e * WPE;
    dst[k]        = (_Float16)W1[e * 512 + k];
    dst[256 + k]  = (_Float16)W1[e * 512 + 256 + k];
    dst[512 + k]  = (_Float16)b1[e * 256 + k];
    dst[768 + k]  = (_Float16)W2[e * 768 + 3 * k];
    dst[1024 + k] = (_Float16)W2[e * 768 + 3 * k + 1];
    dst[1280 + k] = (_Float16)W2[e * 768 + 3 * k + 2];
}

// ---------------------------------------------------------------------------
// Kernel B: in-block counting sort -> global slots + global entry table.
// Entries are wave-sized (<=64 samples), expert-uniform, sentinel-padded.
// ---------------------------------------------------------------------------
__global__ __launch_bounds__(STPB) void sort_kernel(
    const float2* __restrict__ samples, int N,
    int2* __restrict__ slots, int4* __restrict__ entries) {
    __shared__ int sHist[NEXP];
    __shared__ int sOff[NEXP + 1];
    __shared__ int sES[NEXP + 1];

    const int tid = threadIdx.x;
    if (tid < NEXP) sHist[tid] = 0;
    __syncthreads();

    const int base0 = blockIdx.x * SAMP;
    float px[S], py[S]; int eid[S], rank[S], gid[S]; bool act[S];
#pragma unroll
    for (int s = 0; s < S; ++s) {
        gid[s] = base0 + s * STPB + tid;              // coalesced float2
        act[s] = gid[s] < N;
        float2 p = act[s] ? samples[gid[s]] : make_float2(0.f, 0.f);
        px[s] = p.x; py[s] = p.y;
        int i = (int)(p.x * (float)GRID_W); i = i < 0 ? 0 : (i > GRID_W - 1 ? GRID_W - 1 : i);
        int j = (int)(p.y * (float)GRID_H); j = j < 0 ? 0 : (j > GRID_H - 1 ? GRID_H - 1 : j);
        eid[s] = j * GRID_W + i;
        rank[s] = act[s] ? atomicAdd(&sHist[eid[s]], 1) : 0;
    }
    __syncthreads();

    if (tid == 0) {                                   // tiny serial scans
        int acc = 0, ec = 0;
        for (int e = 0; e < NEXP; ++e) {
            sOff[e] = acc; acc += sHist[e];
            sES[e] = ec;  ec  += (sHist[e] + 63) >> 6; // 64-granular entries
        }
        sOff[NEXP] = acc; sES[NEXP] = ec;
    }
    __syncthreads();

    // scatter sorted slots to this block's global region (stays in L2/L3)
#pragma unroll
    for (int s = 0; s < S; ++s) {
        if (act[s]) {
            union { h2 h; int i; } u;
            u.h.x = (_Float16)px[s]; u.h.y = (_Float16)py[s];
            int2 v; v.x = u.i; v.y = gid[s];
            slots[base0 + sOff[eid[s]] + rank[s]] = v;
        }
    }
    // entry table: exactly MAXE entries per block, cnt=0 sentinels at the tail
    if (tid < MAXE) {
        int C = sES[NEXP];                            // <= 48 by construction
        int4 ent; ent.x = 0; ent.y = base0; ent.z = 0; ent.w = 0;
        if (tid < C) {
            int e = 0;
            while (tid >= sES[e + 1]) ++e;            // <=16 iters, once
            int j = tid - sES[e];
            ent.x = e;
            ent.y = base0 + sOff[e] + j * 64;
            ent.z = min(64, sHist[e] - j * 64);
        }
        entries[blockIdx.x * MAXE + tid] = ent;
    }
}

// Per 16-B uniform load: 8 fp16 weights = 4 k-pairs.
union H8 { float4 f; h2 p[4]; };

// ---------------------------------------------------------------------------
// Kernel C: flat MLP. One wave = one expert-uniform entry (<=64 samples).
// No LDS, no barriers; ~6 waves/SIMD so weight-load latency hides under the
// staggered packed-fp16 VALU streams of neighboring waves.
// ---------------------------------------------------------------------------
__global__ __launch_bounds__(MTPB) void mlp_kernel(
    const _Float16* __restrict__ wsW, const int2* __restrict__ slots,
    const int4* __restrict__ entries, const float* __restrict__ b2,
    float* __restrict__ out, int NE) {
    const int g = blockIdx.x * MWAVES + (threadIdx.x >> 6);
    const int lane = threadIdx.x & 63;
    if (g >= NE) return;

    int4 ent = entries[g];
    int e   = __builtin_amdgcn_readfirstlane(ent.x);
    int bas = __builtin_amdgcn_readfirstlane(ent.y);
    int cnt = __builtin_amdgcn_readfirstlane(ent.z);
    if (cnt == 0) return;                             // sentinel: wave-uniform exit

    int2 v = slots[bas + lane];                       // slots region has +64 pad
    union { int i; h2 h; } u; u.i = v.x;
    h2 px2; px2.x = u.h.x; px2.y = u.h.x;
    h2 py2; py2.x = u.h.y; py2.y = u.h.y;
    int qg = v.y;

    float y0 = b2[3 * e], y1 = b2[3 * e + 1], y2 = b2[3 * e + 2];
    const float4* W4 = (const float4*)(wsW + e * WPE);   // wave-uniform base

#pragma unroll 2
    for (int b = 0; b < 32; ++b) {                    // 8 k's per batch
        H8 wa, wb, bb, u0, u1, u2;
        wa.f = W4[b];         // W1 row x
        wb.f = W4[32 + b];    // W1 row y
        bb.f = W4[64 + b];    // b1
        u0.f = W4[96 + b];    // W2 col 0
        u1.f = W4[128 + b];   // W2 col 1
        u2.f = W4[160 + b];   // W2 col 2
#pragma unroll
        for (int j = 0; j < 4; ++j) {
            h2 h = __builtin_elementwise_fma(px2, wa.p[j],
                   __builtin_elementwise_fma(py2, wb.p[j], bb.p[j]));
            h2 z = (h2)(_Float16)0.0f;
            h = __builtin_elementwise_max(h, z);
#if __has_builtin(__builtin_amdgcn_fdot2)
            y0 = __builtin_amdgcn_fdot2(h, u0.p[j], y0, false);
            y1 = __builtin_amdgcn_fdot2(h, u1.p[j], y1, false);
            y2 = __builtin_amdgcn_fdot2(h, u2.p[j], y2, false);
#else
            y0 += (float)h.x * (float)u0.p[j].x + (float)h.y * (float)u0.p[j].y;
            y1 += (float)h.x * (float)u1.p[j].x + (float)h.y * (float)u1.p[j].y;
            y2 += (float)h.x * (float)u2.p[j].x + (float)h.y * (float)u2.p[j].y;
#endif
        }
    }

    if (lane < cnt) {
        int i3 = 3 * qg;
        out[i3 + 0] = y0;
        out[i3 + 1] = y1;
        out[i3 + 2] = y2;
    }
}

// ---------------------------------------------------------------------------
extern "C" void kernel_launch(void* const* d_in, const int* in_sizes, int n_in,
                              void* d_out, int out_size, void* d_ws, size_t ws_size,
                              hipStream_t stream) {
    const float* samples = (const float*)d_in[0];
    const float* W1      = (const float*)d_in[1];
    const float* b1      = (const float*)d_in[2];
    const float* W2      = (const float*)d_in[3];
    const float* b2      = (const float*)d_in[4];
    float* out = (float*)d_out;

    const int N = in_sizes[0] / 2;
    _Float16* wsW   = (_Float16*)d_ws;
    int4*     ents  = (int4*)((char*)d_ws + WSOFF_ENT);
    int2*     slots = (int2*)((char*)d_ws + WSOFF_SLOT);

    convert_kernel<<<NEXP, 256, 0, stream>>>(W1, b1, W2, wsW);

    const int nsb = (N + SAMP - 1) / SAMP;            // 256 @ N=524288
    sort_kernel<<<nsb, STPB, 0, stream>>>((const float2*)samples, N, slots, ents);

    const int NE = nsb * MAXE;                        // 12288 wave-entries
    mlp_kernel<<<(NE + MWAVES - 1) / MWAVES, MTPB, 0, stream>>>(
        wsW, slots, ents, b2, out, NE);
}

// Round 9
// 91.356 us; speedup vs baseline: 1.0055x; 1.0055x over previous
//
#include <hip/hip_runtime.h>

typedef _Float16 h2 __attribute__((ext_vector_type(2)));

#define GRID_W 4
#define GRID_H 4
#define NEXP   16
#define HID    256
#define TPB    512            // 8 waves/block -> 2 blocks/CU
#define S      4
#define SAMP   (TPB * S)      // 2048 samples per block (keeps padding at ~25%)
#define NWAVE  (TPB / 64)     // 8
#define WPE    1536           // fp16 halves per expert in ws
#define GR     192            // entry granularity (1..3 sub-waves)
#define MAXENT 32             // C <= 16 + 2048/192 = 26

// ---- LDS: sort structures only (~18.5 KB -> 2 blocks/CU) ----
#define NSLOT  (SAMP + GR)
#define OFFB_I (NSLOT * 8)
#define LDS_BYTES (OFFB_I + 4 * (16 + 17 + 17 + 3 * MAXENT + 1))

// ---------------------------------------------------------------------------
// Kernel A: weights fp32 -> fp16 into ws, k-major per expert:
// [0,256)=W1 row x, [256,512)=W1 row y, [512,768)=b1, [768..1536)=W2 cols
// ---------------------------------------------------------------------------
__global__ __launch_bounds__(256) void convert_kernel(
    const float* __restrict__ W1, const float* __restrict__ b1,
    const float* __restrict__ W2, _Float16* __restrict__ wsW) {
    int t = blockIdx.x * 256 + threadIdx.x;     // 4096 threads
    int e = t >> 8, k = t & 255;
    _Float16* dst = wsW + e * WPE;
    dst[k]        = (_Float16)W1[e * 512 + k];
    dst[256 + k]  = (_Float16)W1[e * 512 + 256 + k];
    dst[512 + k]  = (_Float16)b1[e * 256 + k];
    dst[768 + k]  = (_Float16)W2[e * 768 + 3 * k];
    dst[1024 + k] = (_Float16)W2[e * 768 + 3 * k + 1];
    dst[1280 + k] = (_Float16)W2[e * 768 + 3 * k + 2];
}

union H8 { float4 f; h2 p[4]; };
struct WBatch { H8 wa, wb, bb, u0, u1, u2; };   // 8 k's; wave-uniform -> SGPRs

__device__ __forceinline__ WBatch wload(const float4* __restrict__ W4, int b) {
    WBatch w;
    w.wa.f = W4[b];        // W1 row x
    w.wb.f = W4[32 + b];   // W1 row y
    w.bb.f = W4[64 + b];   // b1
    w.u0.f = W4[96 + b];   // W2 col 0
    w.u1.f = W4[128 + b];  // W2 col 1
    w.u2.f = W4[160 + b];  // W2 col 2
    return w;
}

template<int M>
__device__ __forceinline__ void wmath(const WBatch& w, const h2* px2,
                                      const h2* py2, float (*y)[3]) {
#pragma unroll
    for (int j = 0; j < 4; ++j) {
#pragma unroll
        for (int s = 0; s < M; ++s) {
            h2 h = __builtin_elementwise_fma(px2[s], w.wa.p[j],
                   __builtin_elementwise_fma(py2[s], w.wb.p[j], w.bb.p[j]));
            h2 z = (h2)(_Float16)0.0f;
            h = __builtin_elementwise_max(h, z);
            y[s][0] = __builtin_amdgcn_fdot2(h, w.u0.p[j], y[s][0], false);
            y[s][1] = __builtin_amdgcn_fdot2(h, w.u1.p[j], y[s][1], false);
            y[s][2] = __builtin_amdgcn_fdot2(h, w.u2.p[j], y[s][2], false);
        }
    }
}

// Software-pipelined: prefetch batch b+1 (scalar loads) while computing b.
template<int M>
__device__ __forceinline__ void mlp_pass(const float4* __restrict__ W4,
                                         const h2* px2, const h2* py2,
                                         float (*y)[3]) {
    WBatch cur = wload(W4, 0);
#pragma unroll 2
    for (int b = 0; b < 31; ++b) {
        WBatch nxt = wload(W4, b + 1);
        wmath<M>(cur, px2, py2, y);
        cur = nxt;
    }
    wmath<M>(cur, px2, py2, y);
}

// ---------------------------------------------------------------------------
// Fused kernel: in-block counting sort -> expert-uniform waves -> MLP with
// SGPR-resident fp16 weights. 512 blocks -> 2 blocks/CU so one block's
// phase-2 VALU overlaps the other's barriers and load latency.
// ---------------------------------------------------------------------------
__global__ __launch_bounds__(TPB, 4) void fused_moe_kernel(
    const float4* __restrict__ samples4,   // 2 samples per float4
    const _Float16* __restrict__ wsW,
    const float* __restrict__ b2,
    float* __restrict__ out, int N)
{
    extern __shared__ __align__(16) char smem[];
    int2* sSlot = (int2*)smem;
    int*  sI    = (int*)(smem + OFFB_I);
    int* sHist = sI;                  // [16]
    int* sOff  = sI + 16;             // [17]
    int* sES   = sI + 33;             // [17]
    int* sEexp = sI + 50;             // [32]
    int* sEbas = sI + 50 + MAXENT;
    int* sEcnt = sI + 50 + 2 * MAXENT;
    int* sC    = sI + 50 + 3 * MAXENT;

    const int tid = threadIdx.x;
    if (tid < NEXP) sHist[tid] = 0;
    __syncthreads();

    // ---- S1: load 4 samples/thread as 2 float4s; LDS histogram ----
    const int base0 = blockIdx.x * SAMP;
    float px[S], py[S]; int eid[S], rank[S], gid[S]; bool act[S];
#pragma unroll
    for (int r = 0; r < S / 2; ++r) {
        int f4i = (base0 >> 1) + r * TPB + tid;       // float4 index, coalesced
        int g = 2 * (r * TPB + tid);                  // local sample id of pair
        bool in = base0 + g < N;                      // N even -> pair granular
        float4 v = in ? samples4[f4i] : make_float4(0.f, 0.f, 0.f, 0.f);
#pragma unroll
        for (int h = 0; h < 2; ++h) {
            int s = 2 * r + h;
            gid[s] = base0 + g + h;
            act[s] = in;
            float x = h ? v.z : v.x, yv = h ? v.w : v.y;
            px[s] = x; py[s] = yv;
            int i = (int)(x  * (float)GRID_W); i = i < 0 ? 0 : (i > GRID_W - 1 ? GRID_W - 1 : i);
            int j = (int)(yv * (float)GRID_H); j = j < 0 ? 0 : (j > GRID_H - 1 ? GRID_H - 1 : j);
            eid[s] = j * GRID_W + i;
            rank[s] = act[s] ? atomicAdd(&sHist[eid[s]], 1) : 0;
        }
    }
    __syncthreads();

    // ---- S2: serial scans (thread 0) ----
    if (tid == 0) {
        int acc = 0, ec = 0;
        for (int e = 0; e < NEXP; ++e) {
            sOff[e] = acc; acc += sHist[e];
            sES[e] = ec;  ec  += (sHist[e] + GR - 1) / GR;
        }
        sOff[NEXP] = acc; sES[NEXP] = ec; *sC = ec;
    }
    __syncthreads();

    // ---- S3: scatter sorted slots {half2(x,y), gid} + entry table ----
#pragma unroll
    for (int s = 0; s < S; ++s) {
        if (act[s]) {
            union { h2 h; int i; } u;
            u.h.x = (_Float16)px[s]; u.h.y = (_Float16)py[s];
            int2 v; v.x = u.i; v.y = gid[s];
            sSlot[sOff[eid[s]] + rank[s]] = v;
        }
    }
    int C = *sC;
    if (tid < C) {
        int e = 0;
        while (tid >= sES[e + 1]) ++e;
        int j = tid - sES[e];
        sEexp[tid] = e;
        sEbas[tid] = sOff[e] + j * GR;
        sEcnt[tid] = min(GR, sHist[e] - j * GR);
    }
    __syncthreads();

    // ---- Phase 2: expert-uniform waves; weights via pipelined s_loads ----
    const int lane = tid & 63, wv = tid >> 6;
    for (int c = wv; c < C; c += NWAVE) {
        int e   = __builtin_amdgcn_readfirstlane(sEexp[c]);
        int bas = __builtin_amdgcn_readfirstlane(sEbas[c]);
        int cnt = __builtin_amdgcn_readfirstlane(sEcnt[c]);
        const float4* W4 = (const float4*)(wsW + e * WPE);   // uniform base
        float b20 = b2[3 * e], b21 = b2[3 * e + 1], b22 = b2[3 * e + 2];
        int m = (cnt + 63) >> 6;                             // 1..3 sub-waves

        h2 px2[3], py2[3]; int qg[3]; float yy[3][3];
#pragma unroll
        for (int s = 0; s < 3; ++s) {
            if (s < m) {
                int2 v = sSlot[bas + s * 64 + lane];         // pad: in-bounds
                union { int i; h2 h; } u; u.i = v.x;
                px2[s].x = u.h.x; px2[s].y = u.h.x;
                py2[s].x = u.h.y; py2[s].y = u.h.y;
                qg[s] = v.y;
                yy[s][0] = b20; yy[s][1] = b21; yy[s][2] = b22;
            }
        }

        if (m == 3)      mlp_pass<3>(W4, px2, py2, yy);
        else if (m == 2) mlp_pass<2>(W4, px2, py2, yy);
        else             mlp_pass<1>(W4, px2, py2, yy);

#pragma unroll
        for (int s = 0; s < 3; ++s) {
            if (s < m && s * 64 + lane < cnt) {
                int i3 = 3 * qg[s];
                out[i3 + 0] = yy[s][0];
                out[i3 + 1] = yy[s][1];
                out[i3 + 2] = yy[s][2];
            }
        }
    }
}

// ---------------------------------------------------------------------------
extern "C" void kernel_launch(void* const* d_in, const int* in_sizes, int n_in,
                              void* d_out, int out_size, void* d_ws, size_t ws_size,
                              hipStream_t stream) {
    const float* samples = (const float*)d_in[0];
    const float* W1      = (const float*)d_in[1];
    const float* b1      = (const float*)d_in[2];
    const float* W2      = (const float*)d_in[3];
    const float* b2      = (const float*)d_in[4];
    float* out = (float*)d_out;

    const int N = in_sizes[0] / 2;
    _Float16* wsW = (_Float16*)d_ws;                 // 49152 B used

    convert_kernel<<<NEXP, 256, 0, stream>>>(W1, b1, W2, wsW);

    const int nblocks = (N + SAMP - 1) / SAMP;       // 512 @ N=524288
    fused_moe_kernel<<<nblocks, TPB, LDS_BYTES, stream>>>(
        (const float4*)samples, wsW, b2, out, N);
}

// Round 10
// 86.497 us; speedup vs baseline: 1.0619x; 1.0562x over previous
//
#include <hip/hip_runtime.h>

typedef _Float16 h2 __attribute__((ext_vector_type(2)));

#define GRID_W 4
#define GRID_H 4
#define NEXP   16
#define HID    256
#define TPB    1024
#define S      2
#define SAMP   (TPB * S)            // 2048 samples per block
#define NWAVE  (TPB / 64)           // 16 waves
#define WPE    1536                 // fp16 halves per expert in ws
#define GR     192                  // entry granularity (1..3 sub-waves)
#define MAXENT 32

// ---- LDS byte map ----
// [0,     17920): int2 sSlot[2048+192]   {half2(x,y), local_idx}
// [17920, 42496): float sY[2048*3]       y routed back to local order
// [42496, 43084): ints hist/off/es/entries
#define NSLOT   (SAMP + GR)
#define OFFB_Y  (NSLOT * 8)
#define OFFB_I  (OFFB_Y + SAMP * 12)
#define LDS_BYTES (OFFB_I + 4 * (16 + 17 + 17 + 3 * MAXENT + 1))

// ---------------------------------------------------------------------------
// Kernel A: weights fp32 -> fp16 into ws, k-major per expert:
// [0,256)=W1 row x, [256,512)=W1 row y, [512,768)=b1, [768..1536)=W2 cols
// ---------------------------------------------------------------------------
__global__ __launch_bounds__(256) void convert_kernel(
    const float* __restrict__ W1, const float* __restrict__ b1,
    const float* __restrict__ W2, _Float16* __restrict__ wsW) {
    int t = blockIdx.x * 256 + threadIdx.x;     // 4096 threads
    int e = t >> 8, k = t & 255;
    _Float16* dst = wsW + e * WPE;
    dst[k]        = (_Float16)W1[e * 512 + k];
    dst[256 + k]  = (_Float16)W1[e * 512 + 256 + k];
    dst[512 + k]  = (_Float16)b1[e * 256 + k];
    dst[768 + k]  = (_Float16)W2[e * 768 + 3 * k];
    dst[1024 + k] = (_Float16)W2[e * 768 + 3 * k + 1];
    dst[1280 + k] = (_Float16)W2[e * 768 + 3 * k + 2];
}

// Per 16-B uniform load: 8 fp16 weights = 4 k-pairs.
union H8 { float4 f; h2 p[4]; };

template<int M>
__device__ __forceinline__ void mlp_pass(const float4* __restrict__ W4,
                                         const h2* px2, const h2* py2,
                                         float (*y)[3]) {
#pragma unroll 4
    for (int b = 0; b < 32; ++b) {              // 8 k's per batch
        H8 wa, wb, bb, u0, u1, u2;
        wa.f = W4[b];         // W1 row x
        wb.f = W4[32 + b];    // W1 row y
        bb.f = W4[64 + b];    // b1
        u0.f = W4[96 + b];    // W2 col 0 (k-major)
        u1.f = W4[128 + b];   // W2 col 1
        u2.f = W4[160 + b];   // W2 col 2
#pragma unroll
        for (int j = 0; j < 4; ++j) {
#pragma unroll
            for (int s = 0; s < M; ++s) {
                h2 h = __builtin_elementwise_fma(px2[s], wa.p[j],
                       __builtin_elementwise_fma(py2[s], wb.p[j], bb.p[j]));
                h2 z = (h2)(_Float16)0.0f;
                h = __builtin_elementwise_max(h, z);
                y[s][0] = __builtin_amdgcn_fdot2(h, u0.p[j], y[s][0], false);
                y[s][1] = __builtin_amdgcn_fdot2(h, u1.p[j], y[s][1], false);
                y[s][2] = __builtin_amdgcn_fdot2(h, u2.p[j], y[s][2], false);
            }
        }
    }
}

// ---------------------------------------------------------------------------
// Fused kernel (R7 structure): in-block counting sort -> expert-uniform waves
// -> MLP -> NEW: y routed back to local order via LDS, then fully COALESCED
// global stores (the sorted direct-store epilogue was ~64-line-scattered per
// wave — suspected ~15-20 us of TA address processing).
// ---------------------------------------------------------------------------
__global__ __launch_bounds__(TPB) void fused_moe_kernel(
    const float2* __restrict__ samples,
    const _Float16* __restrict__ wsW,
    const float* __restrict__ b2,
    float* __restrict__ out, int N)
{
    extern __shared__ __align__(16) char smem[];
    int2*  sSlot = (int2*)smem;
    float* sY    = (float*)(smem + OFFB_Y);
    int*   sI    = (int*)(smem + OFFB_I);
    int* sHist = sI;                 // [16]
    int* sOff  = sI + 16;            // [17]
    int* sES   = sI + 33;            // [17]
    int* sEexp = sI + 50;            // [32]
    int* sEbas = sI + 50 + MAXENT;
    int* sEcnt = sI + 50 + 2 * MAXENT;
    int* sC    = sI + 50 + 3 * MAXENT;

    const int tid = threadIdx.x;
    if (tid < NEXP) sHist[tid] = 0;
    __syncthreads();

    // ---- S1: load samples, LDS histogram ----
    const int base0 = blockIdx.x * SAMP;
    float px[S], py[S]; int eid[S], rank[S]; bool act[S];
#pragma unroll
    for (int s = 0; s < S; ++s) {
        int gid = base0 + s * TPB + tid;              // coalesced float2
        act[s] = gid < N;
        float2 p = act[s] ? samples[gid] : make_float2(0.f, 0.f);
        px[s] = p.x; py[s] = p.y;
        int i = (int)(p.x * (float)GRID_W); i = i < 0 ? 0 : (i > GRID_W - 1 ? GRID_W - 1 : i);
        int j = (int)(p.y * (float)GRID_H); j = j < 0 ? 0 : (j > GRID_H - 1 ? GRID_H - 1 : j);
        eid[s] = j * GRID_W + i;
        rank[s] = act[s] ? atomicAdd(&sHist[eid[s]], 1) : 0;
    }
    __syncthreads();

    // ---- S2: serial scans (thread 0) ----
    if (tid == 0) {
        int acc = 0, ec = 0;
        for (int e = 0; e < NEXP; ++e) {
            sOff[e] = acc; acc += sHist[e];
            sES[e] = ec;  ec  += (sHist[e] + GR - 1) / GR;
        }
        sOff[NEXP] = acc; sES[NEXP] = ec; *sC = ec;
    }
    __syncthreads();

    // ---- S3: scatter sorted slots {half2(x,y), LOCAL idx} + entry table ----
#pragma unroll
    for (int s = 0; s < S; ++s) {
        if (act[s]) {
            union { h2 h; int i; } u;
            u.h.x = (_Float16)px[s]; u.h.y = (_Float16)py[s];
            int2 v; v.x = u.i; v.y = s * TPB + tid;   // local sample index
            sSlot[sOff[eid[s]] + rank[s]] = v;
        }
    }
    int C = *sC;
    if (tid < C) {
        int e = 0;
        while (tid >= sES[e + 1]) ++e;
        int j = tid - sES[e];
        sEexp[tid] = e;
        sEbas[tid] = sOff[e] + j * GR;
        sEcnt[tid] = min(GR, sHist[e] - j * GR);
    }
    __syncthreads();

    // ---- Phase 2: expert-uniform waves; y written to LDS in local order ----
    const int lane = tid & 63, wv = tid >> 6;
    for (int c = wv; c < C; c += NWAVE) {
        int e   = __builtin_amdgcn_readfirstlane(sEexp[c]);
        int bas = __builtin_amdgcn_readfirstlane(sEbas[c]);
        int cnt = __builtin_amdgcn_readfirstlane(sEcnt[c]);
        const float4* W4 = (const float4*)(wsW + e * WPE);   // uniform base
        float b20 = b2[3 * e], b21 = b2[3 * e + 1], b22 = b2[3 * e + 2];
        int m = (cnt + 63) >> 6;                             // 1..3 sub-waves

        h2 px2[3], py2[3]; int ql[3]; float yy[3][3];
#pragma unroll
        for (int s = 0; s < 3; ++s) {
            if (s < m) {
                int2 v = sSlot[bas + s * 64 + lane];         // pad: in-bounds
                union { int i; h2 h; } u; u.i = v.x;
                px2[s].x = u.h.x; px2[s].y = u.h.x;
                py2[s].x = u.h.y; py2[s].y = u.h.y;
                ql[s] = v.y;
                yy[s][0] = b20; yy[s][1] = b21; yy[s][2] = b22;
            }
        }

        if (m == 3)      mlp_pass<3>(W4, px2, py2, yy);
        else if (m == 2) mlp_pass<2>(W4, px2, py2, yy);
        else             mlp_pass<1>(W4, px2, py2, yy);

#pragma unroll
        for (int s = 0; s < 3; ++s) {
            if (s < m && s * 64 + lane < cnt) {              // guard padding
                int d = 3 * ql[s];                           // LDS scatter: cheap
                sY[d + 0] = yy[s][0];
                sY[d + 1] = yy[s][1];
                sY[d + 2] = yy[s][2];
            }
        }
    }
    __syncthreads();

    // ---- Epilogue: identity dword map sY[d] -> out[base0*3 + d], coalesced ----
    int nv = N - base0; if (nv > SAMP) nv = SAMP;            // valid samples
    int dmax = 3 * nv;
    float* outw = out + (size_t)base0 * 3;
#pragma unroll
    for (int r = 0; r < 3 * S; ++r) {                        // 6 rounds x 1024
        int d = r * TPB + tid;
        if (d < dmax) outw[d] = sY[d];
    }
}

// ---------------------------------------------------------------------------
extern "C" void kernel_launch(void* const* d_in, const int* in_sizes, int n_in,
                              void* d_out, int out_size, void* d_ws, size_t ws_size,
                              hipStream_t stream) {
    const float* samples = (const float*)d_in[0];
    const float* W1      = (const float*)d_in[1];
    const float* b1      = (const float*)d_in[2];
    const float* W2      = (const float*)d_in[3];
    const float* b2      = (const float*)d_in[4];
    float* out = (float*)d_out;

    const int N = in_sizes[0] / 2;
    _Float16* wsW = (_Float16*)d_ws;                 // 49152 B used

    convert_kernel<<<NEXP, 256, 0, stream>>>(W1, b1, W2, wsW);

    const int nblocks = (N + SAMP - 1) / SAMP;       // 256 @ N=524288
    fused_moe_kernel<<<nblocks, TPB, LDS_BYTES, stream>>>(
        (const float2*)samples, wsW, b2, out, N);
}

// Round 11
// 84.360 us; speedup vs baseline: 1.0888x; 1.0253x over previous
//
#include <hip/hip_runtime.h>

typedef _Float16 h2 __attribute__((ext_vector_type(2)));

#define GRID_W 4
#define GRID_H 4
#define NEXP   16
#define HID    256
#define TPB    1024
#define S      2
#define SAMP   (TPB * S)            // 2048 samples per block
#define NWAVE  (TPB / 64)           // 16 waves
#define GR     64                   // entry granularity: every entry = 1 sub-wave
#define MAXENT 48                   // <= 16 + 2048/64

// ---- LDS byte map ----
// [0,     33792): int4 sSlot[2048+64]   {fp32 x, fp32 y, local_idx, pad}
// [33792, 58368): float sY[2048*3]      y routed back to local order
// [58368, 59148): ints hist/off/es/entries
#define NSLOT   (SAMP + GR)
#define OFFB_Y  (NSLOT * 16)
#define OFFB_I  (OFFB_Y + SAMP * 12)
#define LDS_BYTES (OFFB_I + 4 * (16 + 17 + 17 + 3 * MAXENT + 1))

// ---- ws layout (bytes) ----
// [0,    768): float aff[16][12]  {A00,A01,d0, A10,A11,d1, A20,A21,d2, 0,0,0}
// [768,  832): int   m2[16]       padded pair count (multiple of 4)
// [4096, 53248): fp16 mixed lists: per expert 768 h2 (6 arrays x 128 h2):
//               A2[0,128) B2[128,256) C2[256,384) U0[384,512) U1[512,640) U2[640,768)
#define WPE_H2  768                 // h2 per expert
#define WSOFF_M2  768
#define WSOFF_MIX 4096

union H8 { float4 f; h2 p[4]; };

// ---------------------------------------------------------------------------
// Kernel A: per (expert, k) classify relu(a x + b y + c) over the expert's
// cell. always-on -> fold into per-expert affine (fp32, exact); always-off ->
// drop; mixed -> append to packed fp16 pair-list (zero-padded to 4-pair mult).
// One block per expert.
// ---------------------------------------------------------------------------
__global__ __launch_bounds__(256) void prep_kernel(
    const float* __restrict__ W1, const float* __restrict__ b1,
    const float* __restrict__ W2, const float* __restrict__ b2,
    float* __restrict__ wsAff, int* __restrict__ wsM2,
    _Float16* __restrict__ wsMix) {
    __shared__ float sA[9];
    __shared__ int sCnt;
    __shared__ _Float16 tA[256], tB[256], tC[256], tU0[256], tU1[256], tU2[256];

    const int e = blockIdx.x, k = threadIdx.x;
    if (k < 9) sA[k] = 0.f;
    if (k == 0) sCnt = 0;
    __syncthreads();

    float a  = W1[e * 512 + k];            // W1[e][0][k]
    float b  = W1[e * 512 + 256 + k];      // W1[e][1][k]
    float c  = b1[e * 256 + k];
    float u0 = W2[e * 768 + 3 * k];
    float u1 = W2[e * 768 + 3 * k + 1];
    float u2 = W2[e * 768 + 3 * k + 2];

    int ci = e & 3, cj = e >> 2;           // e = j*4 + i
    float x0 = ci * 0.25f, x1 = x0 + 0.25f;
    float y0 = cj * 0.25f, y1 = y0 + 0.25f;
    // linear fn -> extrema at corners
    float vmin = fminf(a * x0, a * x1) + fminf(b * y0, b * y1) + c;
    float vmax = fmaxf(a * x0, a * x1) + fmaxf(b * y0, b * y1) + c;

    if (vmin >= 0.f) {                     // always-on: exact affine fold
        atomicAdd(&sA[0], u0 * a); atomicAdd(&sA[1], u0 * b); atomicAdd(&sA[2], u0 * c);
        atomicAdd(&sA[3], u1 * a); atomicAdd(&sA[4], u1 * b); atomicAdd(&sA[5], u1 * c);
        atomicAdd(&sA[6], u2 * a); atomicAdd(&sA[7], u2 * b); atomicAdd(&sA[8], u2 * c);
    } else if (vmax > 0.f) {               // mixed: needs per-sample relu
        int p = atomicAdd(&sCnt, 1);
        tA[p] = (_Float16)a;  tB[p] = (_Float16)b;  tC[p] = (_Float16)c;
        tU0[p] = (_Float16)u0; tU1[p] = (_Float16)u1; tU2[p] = (_Float16)u2;
    }
    __syncthreads();

    int M = sCnt;
    int M2r = (((M + 1) >> 1) + 3) & ~3;   // pairs, padded to multiple of 4 (<=128)
    for (int t = M + k; t < 2 * M2r; t += 256) {   // zero-pad scalar tail
        tA[t] = (_Float16)0.f; tB[t] = (_Float16)0.f; tC[t] = (_Float16)0.f;
        tU0[t] = (_Float16)0.f; tU1[t] = (_Float16)0.f; tU2[t] = (_Float16)0.f;
    }
    __syncthreads();

    h2* dst = (h2*)(wsMix + (size_t)e * (2 * WPE_H2));   // 1536 halves/expert
    if (k < M2r) {
        h2 v;
        v.x = tA[2 * k];  v.y = tA[2 * k + 1];  dst[k]       = v;
        v.x = tB[2 * k];  v.y = tB[2 * k + 1];  dst[128 + k] = v;
        v.x = tC[2 * k];  v.y = tC[2 * k + 1];  dst[256 + k] = v;
        v.x = tU0[2 * k]; v.y = tU0[2 * k + 1]; dst[384 + k] = v;
        v.x = tU1[2 * k]; v.y = tU1[2 * k + 1]; dst[512 + k] = v;
        v.x = tU2[2 * k]; v.y = tU2[2 * k + 1]; dst[640 + k] = v;
    }
    if (k == 0) {
        wsM2[e] = M2r;
        float* af = wsAff + e * 12;
        af[0] = sA[0]; af[1] = sA[1]; af[2] = b2[3 * e]     + sA[2];
        af[3] = sA[3]; af[4] = sA[4]; af[5] = b2[3 * e + 1] + sA[5];
        af[6] = sA[6]; af[7] = sA[7]; af[8] = b2[3 * e + 2] + sA[8];
        af[9] = 0.f; af[10] = 0.f; af[11] = 0.f;
    }
}

// ---------------------------------------------------------------------------
// Fused kernel (R10 sort + epilogue verbatim): in-block counting sort ->
// expert-uniform sub-waves -> affine + mixed-k fp16 loop -> LDS-routed
// coalesced store.
// ---------------------------------------------------------------------------
__global__ __launch_bounds__(TPB) void fused_moe_kernel(
    const float2* __restrict__ samples,
    const float* __restrict__ wsAff, const int* __restrict__ wsM2,
    const _Float16* __restrict__ wsMix,
    float* __restrict__ out, int N)
{
    extern __shared__ __align__(16) char smem[];
    int4*  sSlot = (int4*)smem;
    float* sY    = (float*)(smem + OFFB_Y);
    int*   sI    = (int*)(smem + OFFB_I);
    int* sHist = sI;                 // [16]
    int* sOff  = sI + 16;            // [17]
    int* sES   = sI + 33;            // [17]
    int* sEexp = sI + 50;            // [48]
    int* sEbas = sI + 50 + MAXENT;
    int* sEcnt = sI + 50 + 2 * MAXENT;
    int* sC    = sI + 50 + 3 * MAXENT;

    const int tid = threadIdx.x;
    if (tid < NEXP) sHist[tid] = 0;
    __syncthreads();

    // ---- S1: load samples, LDS histogram ----
    const int base0 = blockIdx.x * SAMP;
    float px[S], py[S]; int eid[S], rank[S]; bool act[S];
#pragma unroll
    for (int s = 0; s < S; ++s) {
        int gid = base0 + s * TPB + tid;              // coalesced float2
        act[s] = gid < N;
        float2 p = act[s] ? samples[gid] : make_float2(0.f, 0.f);
        px[s] = p.x; py[s] = p.y;
        int i = (int)(p.x * (float)GRID_W); i = i < 0 ? 0 : (i > GRID_W - 1 ? GRID_W - 1 : i);
        int j = (int)(p.y * (float)GRID_H); j = j < 0 ? 0 : (j > GRID_H - 1 ? GRID_H - 1 : j);
        eid[s] = j * GRID_W + i;
        rank[s] = act[s] ? atomicAdd(&sHist[eid[s]], 1) : 0;
    }
    __syncthreads();

    // ---- S2: serial scans (thread 0) ----
    if (tid == 0) {
        int acc = 0, ec = 0;
        for (int e = 0; e < NEXP; ++e) {
            sOff[e] = acc; acc += sHist[e];
            sES[e] = ec;  ec  += (sHist[e] + GR - 1) / GR;
        }
        sOff[NEXP] = acc; sES[NEXP] = ec; *sC = ec;
    }
    __syncthreads();

    // ---- S3: scatter sorted slots {fp32 x, fp32 y, local idx} + entries ----
#pragma unroll
    for (int s = 0; s < S; ++s) {
        if (act[s]) {
            int4 v;
            v.x = __float_as_int(px[s]); v.y = __float_as_int(py[s]);
            v.z = s * TPB + tid; v.w = 0;
            sSlot[sOff[eid[s]] + rank[s]] = v;
        }
    }
    int C = *sC;
    if (tid < C) {
        int e = 0;
        while (tid >= sES[e + 1]) ++e;
        int j = tid - sES[e];
        sEexp[tid] = e;
        sEbas[tid] = sOff[e] + j * GR;
        sEcnt[tid] = min(GR, sHist[e] - j * GR);
    }
    __syncthreads();

    // ---- Phase 2: one entry = one expert-uniform sub-wave ----
    const int lane = tid & 63, wv = tid >> 6;
    for (int c = wv; c < C; c += NWAVE) {
        int e   = __builtin_amdgcn_readfirstlane(sEexp[c]);
        int bas = __builtin_amdgcn_readfirstlane(sEbas[c]);
        int cnt = __builtin_amdgcn_readfirstlane(sEcnt[c]);

        int4 v = sSlot[bas + lane];                   // padded: in-bounds
        float x = __int_as_float(v.x), y = __int_as_float(v.y);
        int ql = v.z;

        const float* af = wsAff + e * 12;             // uniform -> s_load
        float y0 = fmaf(x, af[0], fmaf(y, af[1], af[2]));
        float y1 = fmaf(x, af[3], fmaf(y, af[4], af[5]));
        float y2 = fmaf(x, af[6], fmaf(y, af[7], af[8]));

        h2 px2; px2.x = (_Float16)x; px2.y = px2.x;
        h2 py2; py2.x = (_Float16)y; py2.y = py2.x;

        int nb = __builtin_amdgcn_readfirstlane(wsM2[e]) >> 2;  // 4-pair batches
        const float4* Wm = (const float4*)(wsMix + (size_t)e * (2 * WPE_H2));
        for (int bi = 0; bi < nb; ++bi) {
            H8 A, B, Cc, U0, U1, U2;
            A.f  = Wm[bi];        B.f  = Wm[32 + bi];  Cc.f = Wm[64 + bi];
            U0.f = Wm[96 + bi];   U1.f = Wm[128 + bi]; U2.f = Wm[160 + bi];
#pragma unroll
            for (int j = 0; j < 4; ++j) {
                h2 h = __builtin_elementwise_fma(px2, A.p[j],
                       __builtin_elementwise_fma(py2, B.p[j], Cc.p[j]));
                h2 z = (h2)(_Float16)0.0f;
                h = __builtin_elementwise_max(h, z);
#if __has_builtin(__builtin_amdgcn_fdot2)
                y0 = __builtin_amdgcn_fdot2(h, U0.p[j], y0, false);
                y1 = __builtin_amdgcn_fdot2(h, U1.p[j], y1, false);
                y2 = __builtin_amdgcn_fdot2(h, U2.p[j], y2, false);
#else
                y0 += (float)h.x * (float)U0.p[j].x + (float)h.y * (float)U0.p[j].y;
                y1 += (float)h.x * (float)U1.p[j].x + (float)h.y * (float)U1.p[j].y;
                y2 += (float)h.x * (float)U2.p[j].x + (float)h.y * (float)U2.p[j].y;
#endif
            }
        }

        if (lane < cnt) {                             // guard sub-wave padding
            int d = 3 * ql;
            sY[d + 0] = y0; sY[d + 1] = y1; sY[d + 2] = y2;
        }
    }
    __syncthreads();

    // ---- Epilogue: identity dword map sY[d] -> out[base0*3+d], coalesced ----
    int nv = N - base0; if (nv > SAMP) nv = SAMP;
    int dmax = 3 * nv;
    float* outw = out + (size_t)base0 * 3;
#pragma unroll
    for (int r = 0; r < 3 * S; ++r) {
        int d = r * TPB + tid;
        if (d < dmax) outw[d] = sY[d];
    }
}

// ---------------------------------------------------------------------------
extern "C" void kernel_launch(void* const* d_in, const int* in_sizes, int n_in,
                              void* d_out, int out_size, void* d_ws, size_t ws_size,
                              hipStream_t stream) {
    const float* samples = (const float*)d_in[0];
    const float* W1      = (const float*)d_in[1];
    const float* b1      = (const float*)d_in[2];
    const float* W2      = (const float*)d_in[3];
    const float* b2      = (const float*)d_in[4];
    float* out = (float*)d_out;

    const int N = in_sizes[0] / 2;
    float*    wsAff = (float*)d_ws;
    int*      wsM2  = (int*)((char*)d_ws + WSOFF_M2);
    _Float16* wsMix = (_Float16*)((char*)d_ws + WSOFF_MIX);

    prep_kernel<<<NEXP, 256, 0, stream>>>(W1, b1, W2, b2, wsAff, wsM2, wsMix);

    const int nblocks = (N + SAMP - 1) / SAMP;       // 256 @ N=524288
    fused_moe_kernel<<<nblocks, TPB, LDS_BYTES, stream>>>(
        (const float2*)samples, wsAff, wsM2, wsMix, out, N);
}

// Round 12
// 79.901 us; speedup vs baseline: 1.1496x; 1.0558x over previous
//
#include <hip/hip_runtime.h>

typedef _Float16 h2 __attribute__((ext_vector_type(2)));

#define GRID_W 4
#define GRID_H 4
#define NEXP   16
#define HID    256
#define TPB    512
#define S      2
#define SAMP   (TPB * S)        // 1024 samples per block
#define NWAVE  (TPB / 64)       // 8 waves
#define GR     64               // entry granularity: 1 sub-wave per entry
#define MAXENT 33               // 16 + 1024/64 = 32 (+1)

#define CAPP   120              // pairs per mixed array (240 mixed cap; max real ~152)
#define HPA    (2 * CAPP)       // halves per array     = 240
#define HPE    (6 * HPA)        // halves per expert    = 1440
#define F4PA   (CAPP / 4)       // float4 per array     = 30
#define F4PE   (6 * F4PA)       // float4 per expert    = 180

// ---- LDS byte map (total 77208 B -> 2 blocks/CU) ----
// [0,     46080): _Float16 sMix[16][1440]  mixed-k lists, 6 arrays x 240 halves
// [46080, 46848): float sAff[16][12]       affine fold {A00,A01,d0, A10,..}
// [46848, 64256): int4 sSlot[1024+64]      {fp32 x, fp32 y, local_idx, -}
// [64256, 76544): float sY[1024*3]
// [76544, 77208): ints hist16 off17 es17 eexp33 ebas33 ecnt33 C m2[16]
#define OFFB_AFF  46080
#define OFFB_SLOT 46848
#define OFFB_Y    64256
#define OFFB_I    76544
#define NSLOT     (SAMP + GR)
#define LDS_BYTES (OFFB_I + 4 * (16 + 17 + 17 + 3 * MAXENT + 1 + NEXP))

union H8 { float4 f; h2 p[4]; };

__global__ __launch_bounds__(TPB, 4) void fused_moe_kernel(
    const float2* __restrict__ samples,
    const float*  __restrict__ W1, const float* __restrict__ b1,
    const float*  __restrict__ W2, const float* __restrict__ b2,
    float* __restrict__ out, int N)
{
    extern __shared__ __align__(16) char smem[];
    _Float16* sMix = (_Float16*)smem;
    float*    sAff = (float*)(smem + OFFB_AFF);
    int4*     sSlot= (int4*)(smem + OFFB_SLOT);
    float*    sY   = (float*)(smem + OFFB_Y);
    int*      sI   = (int*)(smem + OFFB_I);
    int* sHist = sI;                 // [16]
    int* sOff  = sI + 16;            // [17]
    int* sES   = sI + 33;            // [17]
    int* sEexp = sI + 50;            // [33]
    int* sEbas = sI + 50 + MAXENT;
    int* sEcnt = sI + 50 + 2 * MAXENT;
    int* sC    = sI + 50 + 3 * MAXENT;
    int* sM2   = sI + 51 + 3 * MAXENT;  // [16] mixed 4-pair batch counts

    const int tid = threadIdx.x;
    const int lane = tid & 63, wv = tid >> 6;
    if (tid < NEXP) sHist[tid] = 0;
    __syncthreads();

    // ---- S1: load samples, LDS histogram (atomics over 16 counters) ----
    const int base0 = blockIdx.x * SAMP;
    float px[S], py[S]; int eid[S], rank[S]; bool act[S];
#pragma unroll
    for (int s = 0; s < S; ++s) {
        int gid = base0 + s * TPB + tid;              // coalesced float2
        act[s] = gid < N;
        float2 p = act[s] ? samples[gid] : make_float2(0.f, 0.f);
        px[s] = p.x; py[s] = p.y;
        int i = (int)(p.x * (float)GRID_W); i = i < 0 ? 0 : (i > GRID_W - 1 ? GRID_W - 1 : i);
        int j = (int)(p.y * (float)GRID_H); j = j < 0 ? 0 : (j > GRID_H - 1 ? GRID_H - 1 : j);
        eid[s] = j * GRID_W + i;
        rank[s] = act[s] ? atomicAdd(&sHist[eid[s]], 1) : 0;
    }

    // ---- PREP (runs between S1 and the barrier; no atomics, wave-local) ----
    // Wave w owns experts 2w, 2w+1. Classify relu(ax+by+c) over the cell:
    // always-on -> fp32 affine fold (shuffle-reduced); mixed -> ballot-prefix
    // packed fp16 list in k-order; always-off -> dropped.
#pragma unroll
    for (int ee = 0; ee < 2; ++ee) {
        int e = 2 * wv + ee;
        float aff[9] = {0.f,0.f,0.f,0.f,0.f,0.f,0.f,0.f,0.f};
        int basep = 0;
        _Float16* mb = sMix + e * HPE;
        int ci = e & 3, cj = e >> 2;
        float x0 = ci * 0.25f, x1 = x0 + 0.25f;
        float y0c = cj * 0.25f, y1c = y0c + 0.25f;
#pragma unroll
        for (int kc = 0; kc < 4; ++kc) {
            int k = kc * 64 + lane;
            float a  = W1[e * 512 + k];
            float b  = W1[e * 512 + 256 + k];
            float c  = b1[e * 256 + k];
            float u0 = W2[e * 768 + 3 * k];
            float u1 = W2[e * 768 + 3 * k + 1];
            float u2 = W2[e * 768 + 3 * k + 2];
            float vmin = fminf(a * x0, a * x1) + fminf(b * y0c, b * y1c) + c;
            float vmax = fmaxf(a * x0, a * x1) + fmaxf(b * y0c, b * y1c) + c;
            bool on = vmin >= 0.f;
            bool mixed = (!on) && (vmax > 0.f);
            if (on) {
                aff[0] += u0 * a; aff[1] += u0 * b; aff[2] += u0 * c;
                aff[3] += u1 * a; aff[4] += u1 * b; aff[5] += u1 * c;
                aff[6] += u2 * a; aff[7] += u2 * b; aff[8] += u2 * c;
            }
            unsigned long long mk = __ballot(mixed);
            int pos = basep + __popcll(mk & ((1ull << lane) - 1ull));
            if (mixed && pos < HPA) {
                mb[pos]           = (_Float16)a;
                mb[HPA + pos]     = (_Float16)b;
                mb[2 * HPA + pos] = (_Float16)c;
                mb[3 * HPA + pos] = (_Float16)u0;
                mb[4 * HPA + pos] = (_Float16)u1;
                mb[5 * HPA + pos] = (_Float16)u2;
            }
            basep += __popcll(mk);
        }
        if (basep > HPA) basep = HPA;                 // capacity clamp
        int padTo = (basep + 7) & ~7;                 // pad to 8 halves (4 pairs)
        int idx = basep + lane;
        if (idx < padTo) {
            _Float16 z = (_Float16)0.f;
            mb[idx] = z; mb[HPA + idx] = z; mb[2 * HPA + idx] = z;
            mb[3 * HPA + idx] = z; mb[4 * HPA + idx] = z; mb[5 * HPA + idx] = z;
        }
#pragma unroll
        for (int j = 0; j < 9; ++j) {                 // butterfly wave-reduce
            float v = aff[j];
            for (int d = 1; d < 64; d <<= 1) v += __shfl_xor(v, d);
            aff[j] = v;
        }
        if (lane == 0) {
            float* af = sAff + e * 12;
            af[0] = aff[0]; af[1] = aff[1]; af[2] = aff[2] + b2[3 * e];
            af[3] = aff[3]; af[4] = aff[4]; af[5] = aff[5] + b2[3 * e + 1];
            af[6] = aff[6]; af[7] = aff[7]; af[8] = aff[8] + b2[3 * e + 2];
            af[9] = 0.f; af[10] = 0.f; af[11] = 0.f;
            sM2[e] = padTo >> 3;                      // 4-pair batch count
        }
    }
    __syncthreads();

    // ---- S2: serial scans (thread 0) ----
    if (tid == 0) {
        int acc = 0, ec = 0;
        for (int e = 0; e < NEXP; ++e) {
            sOff[e] = acc; acc += sHist[e];
            sES[e] = ec;  ec  += (sHist[e] + GR - 1) >> 6;
        }
        sOff[NEXP] = acc; sES[NEXP] = ec; *sC = ec;
    }
    __syncthreads();

    // ---- S3: scatter sorted slots {fp32 x, fp32 y, local idx} + entries ----
#pragma unroll
    for (int s = 0; s < S; ++s) {
        if (act[s]) {
            int4 v;
            v.x = __float_as_int(px[s]); v.y = __float_as_int(py[s]);
            v.z = s * TPB + tid; v.w = 0;
            sSlot[sOff[eid[s]] + rank[s]] = v;
        }
    }
    int C = *sC;
    if (tid < C) {
        int e = 0;
        while (tid >= sES[e + 1]) ++e;                // <=16 iters, once
        int j = tid - sES[e];
        sEexp[tid] = e;
        sEbas[tid] = sOff[e] + j * GR;
        sEcnt[tid] = min(GR, sHist[e] - j * GR);
    }
    __syncthreads();

    // ---- Phase 2: one entry = one expert-uniform sub-wave ----
    for (int c = wv; c < C; c += NWAVE) {
        int e   = __builtin_amdgcn_readfirstlane(sEexp[c]);
        int bas = __builtin_amdgcn_readfirstlane(sEbas[c]);
        int cnt = __builtin_amdgcn_readfirstlane(sEcnt[c]);

        int4 v = sSlot[bas + lane];                   // padded region: in-bounds
        float x = __int_as_float(v.x), y = __int_as_float(v.y);
        int ql = v.z;

        const float* af = sAff + e * 12;              // uniform -> LDS broadcast
        float y0 = fmaf(x, af[0], fmaf(y, af[1], af[2]));
        float y1 = fmaf(x, af[3], fmaf(y, af[4], af[5]));
        float y2 = fmaf(x, af[6], fmaf(y, af[7], af[8]));

        h2 px2; px2.x = (_Float16)x; px2.y = px2.x;
        h2 py2; py2.x = (_Float16)y; py2.y = py2.x;

        int nb = __builtin_amdgcn_readfirstlane(sM2[e]);
        const float4* Wm = (const float4*)sMix + e * F4PE;
        for (int bi = 0; bi < nb; ++bi) {
            H8 A, B, Cc, U0, U1, U2;
            A.f  = Wm[bi];
            B.f  = Wm[F4PA + bi];
            Cc.f = Wm[2 * F4PA + bi];
            U0.f = Wm[3 * F4PA + bi];
            U1.f = Wm[4 * F4PA + bi];
            U2.f = Wm[5 * F4PA + bi];
#pragma unroll
            for (int j = 0; j < 4; ++j) {
                h2 h = __builtin_elementwise_fma(px2, A.p[j],
                       __builtin_elementwise_fma(py2, B.p[j], Cc.p[j]));
                h2 z = (h2)(_Float16)0.0f;
                h = __builtin_elementwise_max(h, z);
#if __has_builtin(__builtin_amdgcn_fdot2)
                y0 = __builtin_amdgcn_fdot2(h, U0.p[j], y0, false);
                y1 = __builtin_amdgcn_fdot2(h, U1.p[j], y1, false);
                y2 = __builtin_amdgcn_fdot2(h, U2.p[j], y2, false);
#else
                y0 += (float)h.x * (float)U0.p[j].x + (float)h.y * (float)U0.p[j].y;
                y1 += (float)h.x * (float)U1.p[j].x + (float)h.y * (float)U1.p[j].y;
                y2 += (float)h.x * (float)U2.p[j].x + (float)h.y * (float)U2.p[j].y;
#endif
            }
        }

        if (lane < cnt) {                             // guard sub-wave padding
            int d = 3 * ql;
            sY[d + 0] = y0; sY[d + 1] = y1; sY[d + 2] = y2;
        }
    }
    __syncthreads();

    // ---- Epilogue: identity dword map sY[d] -> out[base0*3+d], coalesced ----
    int nv = N - base0; if (nv > SAMP) nv = SAMP;
    int dmax = 3 * nv;
    float* outw = out + (size_t)base0 * 3;
#pragma unroll
    for (int r = 0; r < 3 * S; ++r) {                 // 6 rounds x 512
        int d = r * TPB + tid;
        if (d < dmax) outw[d] = sY[d];
    }
}

// ---------------------------------------------------------------------------
extern "C" void kernel_launch(void* const* d_in, const int* in_sizes, int n_in,
                              void* d_out, int out_size, void* d_ws, size_t ws_size,
                              hipStream_t stream) {
    const float* samples = (const float*)d_in[0];
    const float* W1      = (const float*)d_in[1];
    const float* b1      = (const float*)d_in[2];
    const float* W2      = (const float*)d_in[3];
    const float* b2      = (const float*)d_in[4];
    float* out = (float*)d_out;

    const int N = in_sizes[0] / 2;
    const int nblocks = (N + SAMP - 1) / SAMP;        // 512 @ N=524288

    fused_moe_kernel<<<nblocks, TPB, LDS_BYTES, stream>>>(
        (const float2*)samples, W1, b1, W2, b2, out, N);
}

// Round 13
// 79.271 us; speedup vs baseline: 1.1587x; 1.0079x over previous
//
#include <hip/hip_runtime.h>

typedef _Float16 h2 __attribute__((ext_vector_type(2)));

#define GRID_W 4
#define GRID_H 4
#define NEXP   16
#define HID    256
#define TPB    512
#define S      2
#define SAMP   (TPB * S)        // 1024 samples per block
#define NWAVE  (TPB / 64)       // 8 waves
#define GR     64               // entry granularity: 1 sub-wave per entry
#define MAXENT 33               // 16 + 1024/64 (+1)

#define CAPP   88               // pairs per mixed array (176 mixed cap; e=0 ~128+-8)
#define HPA    (2 * CAPP)       // halves per array   = 176
#define HPE    (6 * HPA)        // halves per expert  = 1056
#define F4PA   (CAPP / 4)       // float4 per array   = 22
#define F4PE   (6 * F4PA)       // float4 per expert  = 132

// ---- LDS byte map (total 43928 B -> 3 blocks/CU) ----
// [0,     33792): _Float16 sMix[16][1056]  mixed-k lists, 6 arrays x 176 halves
// [33792, 34560): float sAff[16][12]       affine fold
// [34560, 43264): int2 sSlot[1024+64]      {h2(x,y), global gid}
// [43264, 43928): ints hist16 off17 es17 eexp33 ebas33 ecnt33 C m2[16]
#define OFFB_AFF  33792
#define OFFB_SLOT 34560
#define OFFB_I    43264
#define NSLOT     (SAMP + GR)
#define LDS_BYTES (OFFB_I + 4 * (16 + 17 + 17 + 3 * MAXENT + 1 + NEXP))

union H8 { float4 f; h2 p[4]; };

__global__ __launch_bounds__(TPB, 6) void fused_moe_kernel(
    const float2* __restrict__ samples,
    const float*  __restrict__ W1, const float* __restrict__ b1,
    const float*  __restrict__ W2, const float* __restrict__ b2,
    float* __restrict__ out, int N)
{
    extern __shared__ __align__(16) char smem[];
    _Float16* sMix = (_Float16*)smem;
    float*    sAff = (float*)(smem + OFFB_AFF);
    int2*     sSlot= (int2*)(smem + OFFB_SLOT);
    int*      sI   = (int*)(smem + OFFB_I);
    int* sHist = sI;                 // [16]
    int* sOff  = sI + 16;            // [17]
    int* sES   = sI + 33;            // [17]
    int* sEexp = sI + 50;            // [33]
    int* sEbas = sI + 50 + MAXENT;
    int* sEcnt = sI + 50 + 2 * MAXENT;
    int* sC    = sI + 50 + 3 * MAXENT;
    int* sM2   = sI + 51 + 3 * MAXENT;  // [16] 4-pair batch counts

    const int tid = threadIdx.x;
    const int lane = tid & 63, wv = tid >> 6;
    if (tid < NEXP) sHist[tid] = 0;
    __syncthreads();

    // ---- S1: load samples, LDS histogram ----
    const int base0 = blockIdx.x * SAMP;
    float px[S], py[S]; int eid[S], rank[S], gid[S]; bool act[S];
#pragma unroll
    for (int s = 0; s < S; ++s) {
        gid[s] = base0 + s * TPB + tid;               // coalesced float2
        act[s] = gid[s] < N;
        float2 p = act[s] ? samples[gid[s]] : make_float2(0.f, 0.f);
        px[s] = p.x; py[s] = p.y;
        int i = (int)(p.x * (float)GRID_W); i = i < 0 ? 0 : (i > GRID_W - 1 ? GRID_W - 1 : i);
        int j = (int)(p.y * (float)GRID_H); j = j < 0 ? 0 : (j > GRID_H - 1 ? GRID_H - 1 : j);
        eid[s] = j * GRID_W + i;
        rank[s] = act[s] ? atomicAdd(&sHist[eid[s]], 1) : 0;
    }

    // ---- PREP (fills the atomic/barrier gap; wave-local, no atomics) ----
    // Wave w owns experts 2w, 2w+1: classify relu(ax+by+c) over the cell;
    // always-on -> fp32 affine fold (butterfly-reduced); mixed -> ballot-
    // prefix packed fp16 list; always-off -> dropped.
#pragma unroll
    for (int ee = 0; ee < 2; ++ee) {
        int e = 2 * wv + ee;
        float aff[9] = {0.f,0.f,0.f,0.f,0.f,0.f,0.f,0.f,0.f};
        int basep = 0;
        _Float16* mb = sMix + e * HPE;
        int ci = e & 3, cj = e >> 2;
        float x0 = ci * 0.25f, x1 = x0 + 0.25f;
        float y0c = cj * 0.25f, y1c = y0c + 0.25f;
#pragma unroll
        for (int kc = 0; kc < 4; ++kc) {
            int k = kc * 64 + lane;
            float a  = W1[e * 512 + k];
            float b  = W1[e * 512 + 256 + k];
            float c  = b1[e * 256 + k];
            float u0 = W2[e * 768 + 3 * k];
            float u1 = W2[e * 768 + 3 * k + 1];
            float u2 = W2[e * 768 + 3 * k + 2];
            float vmin = fminf(a * x0, a * x1) + fminf(b * y0c, b * y1c) + c;
            float vmax = fmaxf(a * x0, a * x1) + fmaxf(b * y0c, b * y1c) + c;
            bool on = vmin >= 0.f;
            bool mixed = (!on) && (vmax > 0.f);
            if (on) {
                aff[0] += u0 * a; aff[1] += u0 * b; aff[2] += u0 * c;
                aff[3] += u1 * a; aff[4] += u1 * b; aff[5] += u1 * c;
                aff[6] += u2 * a; aff[7] += u2 * b; aff[8] += u2 * c;
            }
            unsigned long long mk = __ballot(mixed);
            int pos = basep + __popcll(mk & ((1ull << lane) - 1ull));
            if (mixed && pos < HPA) {
                mb[pos]           = (_Float16)a;
                mb[HPA + pos]     = (_Float16)b;
                mb[2 * HPA + pos] = (_Float16)c;
                mb[3 * HPA + pos] = (_Float16)u0;
                mb[4 * HPA + pos] = (_Float16)u1;
                mb[5 * HPA + pos] = (_Float16)u2;
            }
            basep += __popcll(mk);
        }
        if (basep > HPA) basep = HPA;                 // capacity clamp
        int padTo = (basep + 7) & ~7;                 // pad to 4-pair multiple
        int idx = basep + lane;
        if (idx < padTo) {
            _Float16 z = (_Float16)0.f;
            mb[idx] = z; mb[HPA + idx] = z; mb[2 * HPA + idx] = z;
            mb[3 * HPA + idx] = z; mb[4 * HPA + idx] = z; mb[5 * HPA + idx] = z;
        }
#pragma unroll
        for (int j = 0; j < 9; ++j) {                 // butterfly wave-reduce
            float v = aff[j];
            for (int d = 1; d < 64; d <<= 1) v += __shfl_xor(v, d);
            aff[j] = v;
        }
        if (lane == 0) {
            float* af = sAff + e * 12;
            af[0] = aff[0]; af[1] = aff[1]; af[2] = aff[2] + b2[3 * e];
            af[3] = aff[3]; af[4] = aff[4]; af[5] = aff[5] + b2[3 * e + 1];
            af[6] = aff[6]; af[7] = aff[7]; af[8] = aff[8] + b2[3 * e + 2];
            af[9] = 0.f; af[10] = 0.f; af[11] = 0.f;
            sM2[e] = padTo >> 3;                      // 4-pair batch count
        }
    }
    __syncthreads();

    // ---- S2: serial scans (thread 0) ----
    if (tid == 0) {
        int acc = 0, ec = 0;
        for (int e = 0; e < NEXP; ++e) {
            sOff[e] = acc; acc += sHist[e];
            sES[e] = ec;  ec  += (sHist[e] + GR - 1) >> 6;
        }
        sOff[NEXP] = acc; sES[NEXP] = ec; *sC = ec;
    }
    __syncthreads();

    // ---- S3: scatter sorted slots {h2(x,y), gid} + entry table ----
#pragma unroll
    for (int s = 0; s < S; ++s) {
        if (act[s]) {
            union { h2 h; int i; } u;
            u.h.x = (_Float16)px[s]; u.h.y = (_Float16)py[s];
            int2 v; v.x = u.i; v.y = gid[s];
            sSlot[sOff[eid[s]] + rank[s]] = v;
        }
    }
    int C = *sC;
    if (tid < C) {
        int e = 0;
        while (tid >= sES[e + 1]) ++e;                // <=16 iters, once
        int j = tid - sES[e];
        sEexp[tid] = e;
        sEbas[tid] = sOff[e] + j * GR;
        sEcnt[tid] = min(GR, sHist[e] - j * GR);
    }
    __syncthreads();

    // ---- Phase 2: one entry = one expert-uniform sub-wave; direct stores
    // (R10 measured scattered stores == LDS-routed coalesced: take free path)
    for (int c = wv; c < C; c += NWAVE) {
        int e   = __builtin_amdgcn_readfirstlane(sEexp[c]);
        int bas = __builtin_amdgcn_readfirstlane(sEbas[c]);
        int cnt = __builtin_amdgcn_readfirstlane(sEcnt[c]);

        int2 v = sSlot[bas + lane];                   // padded region: in-bounds
        union { int i; h2 h; } uxy; uxy.i = v.x;
        float x = (float)uxy.h.x, y = (float)uxy.h.y;
        int qg = v.y;

        const float* af = sAff + e * 12;              // uniform LDS broadcast
        float y0 = fmaf(x, af[0], fmaf(y, af[1], af[2]));
        float y1 = fmaf(x, af[3], fmaf(y, af[4], af[5]));
        float y2 = fmaf(x, af[6], fmaf(y, af[7], af[8]));

        h2 px2; px2.x = uxy.h.x; px2.y = uxy.h.x;
        h2 py2; py2.x = uxy.h.y; py2.y = uxy.h.y;

        int nb = __builtin_amdgcn_readfirstlane(sM2[e]);
        const float4* Wm = (const float4*)sMix + e * F4PE;
        for (int bi = 0; bi < nb; ++bi) {
            H8 A, B, Cc, U0, U1, U2;
            A.f  = Wm[bi];
            B.f  = Wm[F4PA + bi];
            Cc.f = Wm[2 * F4PA + bi];
            U0.f = Wm[3 * F4PA + bi];
            U1.f = Wm[4 * F4PA + bi];
            U2.f = Wm[5 * F4PA + bi];
#pragma unroll
            for (int j = 0; j < 4; ++j) {
                h2 h = __builtin_elementwise_fma(px2, A.p[j],
                       __builtin_elementwise_fma(py2, B.p[j], Cc.p[j]));
                h2 z = (h2)(_Float16)0.0f;
                h = __builtin_elementwise_max(h, z);
#if __has_builtin(__builtin_amdgcn_fdot2)
                y0 = __builtin_amdgcn_fdot2(h, U0.p[j], y0, false);
                y1 = __builtin_amdgcn_fdot2(h, U1.p[j], y1, false);
                y2 = __builtin_amdgcn_fdot2(h, U2.p[j], y2, false);
#else
                y0 += (float)h.x * (float)U0.p[j].x + (float)h.y * (float)U0.p[j].y;
                y1 += (float)h.x * (float)U1.p[j].x + (float)h.y * (float)U1.p[j].y;
                y2 += (float)h.x * (float)U2.p[j].x + (float)h.y * (float)U2.p[j].y;
#endif
            }
        }

        if (lane < cnt) {                             // guard sub-wave padding
            int d = 3 * qg;
            out[d + 0] = y0; out[d + 1] = y1; out[d + 2] = y2;
        }
    }
}

// ---------------------------------------------------------------------------
extern "C" void kernel_launch(void* const* d_in, const int* in_sizes, int n_in,
                              void* d_out, int out_size, void* d_ws, size_t ws_size,
                              hipStream_t stream) {
    const float* samples = (const float*)d_in[0];
    const float* W1      = (const float*)d_in[1];
    const float* b1      = (const float*)d_in[2];
    const float* W2      = (const float*)d_in[3];
    const float* b2      = (const float*)d_in[4];
    float* out = (float*)d_out;

    const int N = in_sizes[0] / 2;
    const int nblocks = (N + SAMP - 1) / SAMP;        // 512 @ N=524288

    fused_moe_kernel<<<nblocks, TPB, LDS_BYTES, stream>>>(
        (const float2*)samples, W1, b1, W2, b2, out, N);
}

// Round 14
// 77.900 us; speedup vs baseline: 1.1791x; 1.0176x over previous
//
#include <hip/hip_runtime.h>

typedef _Float16 h2 __attribute__((ext_vector_type(2)));

#define GRID_W 4
#define GRID_H 4
#define NEXP   16
#define HID    256
#define TPB    512
#define S      2
#define SAMP   (TPB * S)        // 1024 samples per block
#define NWAVE  (TPB / 64)       // 8 waves
#define GR     64               // entry granularity: 1 sub-wave per entry
#define MAXENT 33               // 16 + 1024/64 (+1)

#define CAPP   88               // pairs per mixed array (176 cap; e=0 ~128+-8)
#define HPA    (2 * CAPP)       // halves per array   = 176
#define HPE    (6 * HPA)        // halves per expert  = 1056
#define F4PA   (CAPP / 4)       // float4 per array   = 22
#define F4PE   (6 * F4PA)       // float4 per expert  = 132

// ---- ws layout (bytes) ----
// [0,    768): float aff[16][12]
// [768,  832): int   m2[16]        4-pair batch counts
// [1024, 34816): _Float16 mix[16][1056]  6 arrays x 176 halves per expert
#define WSOFF_M2  768
#define WSOFF_MIX 1024

// ---- main-kernel LDS (~9.3 KB -> wave-limited 4 blocks/CU) ----
#define NSLOT  (SAMP + GR)
#define OFFB_I (NSLOT * 8)
#define LDS_BYTES (OFFB_I + 4 * (16 + 17 + 17 + 3 * MAXENT + 1))

union H8 { float4 f; h2 p[4]; };

// ---------------------------------------------------------------------------
// Prep: one wave per expert. Classify relu(ax+by+c) over the expert's cell:
// always-on -> fp32 affine fold (butterfly-reduced); mixed -> ballot-prefix
// packed fp16 list (k-order, zero-padded to 4-pair multiple); off -> dropped.
// Runs ONCE (was redundantly recomputed in all 512 blocks).
// ---------------------------------------------------------------------------
__global__ __launch_bounds__(64) void prep_kernel(
    const float* __restrict__ W1, const float* __restrict__ b1,
    const float* __restrict__ W2, const float* __restrict__ b2,
    float* __restrict__ wsAff, int* __restrict__ wsM2,
    _Float16* __restrict__ wsMix) {
    const int e = blockIdx.x, lane = threadIdx.x;
    float aff[9] = {0.f,0.f,0.f,0.f,0.f,0.f,0.f,0.f,0.f};
    int basep = 0;
    _Float16* mb = wsMix + e * HPE;
    int ci = e & 3, cj = e >> 2;
    float x0 = ci * 0.25f, x1 = x0 + 0.25f;
    float y0c = cj * 0.25f, y1c = y0c + 0.25f;
#pragma unroll
    for (int kc = 0; kc < 4; ++kc) {
        int k = kc * 64 + lane;
        float a  = W1[e * 512 + k];
        float b  = W1[e * 512 + 256 + k];
        float c  = b1[e * 256 + k];
        float u0 = W2[e * 768 + 3 * k];
        float u1 = W2[e * 768 + 3 * k + 1];
        float u2 = W2[e * 768 + 3 * k + 2];
        float vmin = fminf(a * x0, a * x1) + fminf(b * y0c, b * y1c) + c;
        float vmax = fmaxf(a * x0, a * x1) + fmaxf(b * y0c, b * y1c) + c;
        bool on = vmin >= 0.f;
        bool mixed = (!on) && (vmax > 0.f);
        if (on) {
            aff[0] += u0 * a; aff[1] += u0 * b; aff[2] += u0 * c;
            aff[3] += u1 * a; aff[4] += u1 * b; aff[5] += u1 * c;
            aff[6] += u2 * a; aff[7] += u2 * b; aff[8] += u2 * c;
        }
        unsigned long long mk = __ballot(mixed);
        int pos = basep + __popcll(mk & ((1ull << lane) - 1ull));
        if (mixed && pos < HPA) {
            mb[pos]           = (_Float16)a;
            mb[HPA + pos]     = (_Float16)b;
            mb[2 * HPA + pos] = (_Float16)c;
            mb[3 * HPA + pos] = (_Float16)u0;
            mb[4 * HPA + pos] = (_Float16)u1;
            mb[5 * HPA + pos] = (_Float16)u2;
        }
        basep += __popcll(mk);
    }
    if (basep > HPA) basep = HPA;                 // capacity clamp
    int padTo = (basep + 7) & ~7;                 // pad to 4-pair multiple
    int idx = basep + lane;
    if (idx < padTo) {
        _Float16 z = (_Float16)0.f;
        mb[idx] = z; mb[HPA + idx] = z; mb[2 * HPA + idx] = z;
        mb[3 * HPA + idx] = z; mb[4 * HPA + idx] = z; mb[5 * HPA + idx] = z;
    }
#pragma unroll
    for (int j = 0; j < 9; ++j) {                 // butterfly wave-reduce
        float v = aff[j];
        for (int d = 1; d < 64; d <<= 1) v += __shfl_xor(v, d);
        aff[j] = v;
    }
    if (lane == 0) {
        float* af = wsAff + e * 12;
        af[0] = aff[0]; af[1] = aff[1]; af[2] = aff[2] + b2[3 * e];
        af[3] = aff[3]; af[4] = aff[4]; af[5] = aff[5] + b2[3 * e + 1];
        af[6] = aff[6]; af[7] = aff[7]; af[8] = aff[8] + b2[3 * e + 2];
        af[9] = 0.f; af[10] = 0.f; af[11] = 0.f;
        wsM2[e] = padTo >> 3;                     // 4-pair batch count
    }
}

// ---------------------------------------------------------------------------
// Main kernel: in-block counting sort (tiny LDS) -> expert-uniform sub-waves
// -> affine + mixed-k fp16 loop with s_load weights from ws -> direct stores.
// ---------------------------------------------------------------------------
__global__ __launch_bounds__(TPB, 8) void fused_moe_kernel(
    const float2* __restrict__ samples,
    const float* __restrict__ wsAff, const int* __restrict__ wsM2,
    const _Float16* __restrict__ wsMix,
    float* __restrict__ out, int N)
{
    extern __shared__ __align__(16) char smem[];
    int2* sSlot = (int2*)smem;
    int*  sI    = (int*)(smem + OFFB_I);
    int* sHist = sI;                 // [16]
    int* sOff  = sI + 16;            // [17]
    int* sES   = sI + 33;            // [17]
    int* sEexp = sI + 50;            // [33]
    int* sEbas = sI + 50 + MAXENT;
    int* sEcnt = sI + 50 + 2 * MAXENT;
    int* sC    = sI + 50 + 3 * MAXENT;

    const int tid = threadIdx.x;
    const int lane = tid & 63, wv = tid >> 6;
    if (tid < NEXP) sHist[tid] = 0;
    __syncthreads();

    // ---- S1: load samples, LDS histogram ----
    const int base0 = blockIdx.x * SAMP;
    float px[S], py[S]; int eid[S], rank[S], gid[S]; bool act[S];
#pragma unroll
    for (int s = 0; s < S; ++s) {
        gid[s] = base0 + s * TPB + tid;               // coalesced float2
        act[s] = gid[s] < N;
        float2 p = act[s] ? samples[gid[s]] : make_float2(0.f, 0.f);
        px[s] = p.x; py[s] = p.y;
        int i = (int)(p.x * (float)GRID_W); i = i < 0 ? 0 : (i > GRID_W - 1 ? GRID_W - 1 : i);
        int j = (int)(p.y * (float)GRID_H); j = j < 0 ? 0 : (j > GRID_H - 1 ? GRID_H - 1 : j);
        eid[s] = j * GRID_W + i;
        rank[s] = act[s] ? atomicAdd(&sHist[eid[s]], 1) : 0;
    }
    __syncthreads();

    // ---- S2: parallel scans in wave 0 (was serial thread-0 loop) ----
    if (wv == 0) {
        int h  = (lane < NEXP) ? sHist[lane] : 0;
        int ec = (lane < NEXP) ? ((h + 63) >> 6) : 0;
        int sh = h, se = ec;
#pragma unroll
        for (int d = 1; d < 16; d <<= 1) {
            int th = __shfl_up(sh, d), te = __shfl_up(se, d);
            if (lane >= d) { sh += th; se += te; }
        }
        if (lane < NEXP) { sOff[lane] = sh - h; sES[lane] = se - ec; }
        if (lane == NEXP - 1) { sOff[NEXP] = sh; sES[NEXP] = se; *sC = se; }
    }
    __syncthreads();

    // ---- S3: scatter sorted slots {h2(x,y), gid} + entry table ----
#pragma unroll
    for (int s = 0; s < S; ++s) {
        if (act[s]) {
            union { h2 h; int i; } u;
            u.h.x = (_Float16)px[s]; u.h.y = (_Float16)py[s];
            int2 v; v.x = u.i; v.y = gid[s];
            sSlot[sOff[eid[s]] + rank[s]] = v;
        }
    }
    int C = *sC;
    if (tid < C) {
        int e = 0;
        while (tid >= sES[e + 1]) ++e;                // <=16 iters, once
        int j = tid - sES[e];
        sEexp[tid] = e;
        sEbas[tid] = sOff[e] + j * GR;
        sEcnt[tid] = min(GR, sHist[e] - j * GR);
    }
    __syncthreads();

    // ---- Phase 2: one entry = one expert-uniform sub-wave; weights via
    // wave-uniform s_load from ws (R6<->R7: scalar pipe == LDS broadcast) ----
    for (int c = wv; c < C; c += NWAVE) {
        int e   = __builtin_amdgcn_readfirstlane(sEexp[c]);
        int bas = __builtin_amdgcn_readfirstlane(sEbas[c]);
        int cnt = __builtin_amdgcn_readfirstlane(sEcnt[c]);

        int2 v = sSlot[bas + lane];                   // padded region: in-bounds
        union { int i; h2 h; } uxy; uxy.i = v.x;
        float x = (float)uxy.h.x, y = (float)uxy.h.y;
        int qg = v.y;

        const float* af = wsAff + e * 12;             // uniform -> s_load
        float y0 = fmaf(x, af[0], fmaf(y, af[1], af[2]));
        float y1 = fmaf(x, af[3], fmaf(y, af[4], af[5]));
        float y2 = fmaf(x, af[6], fmaf(y, af[7], af[8]));

        h2 px2; px2.x = uxy.h.x; px2.y = uxy.h.x;
        h2 py2; py2.x = uxy.h.y; py2.y = uxy.h.y;

        int nb = __builtin_amdgcn_readfirstlane(wsM2[e]);
        const float4* Wm = (const float4*)wsMix + e * F4PE;
        for (int bi = 0; bi < nb; ++bi) {
            H8 A, B, Cc, U0, U1, U2;
            A.f  = Wm[bi];
            B.f  = Wm[F4PA + bi];
            Cc.f = Wm[2 * F4PA + bi];
            U0.f = Wm[3 * F4PA + bi];
            U1.f = Wm[4 * F4PA + bi];
            U2.f = Wm[5 * F4PA + bi];
#pragma unroll
            for (int j = 0; j < 4; ++j) {
                h2 h = __builtin_elementwise_fma(px2, A.p[j],
                       __builtin_elementwise_fma(py2, B.p[j], Cc.p[j]));
                h2 z = (h2)(_Float16)0.0f;
                h = __builtin_elementwise_max(h, z);
#if __has_builtin(__builtin_amdgcn_fdot2)
                y0 = __builtin_amdgcn_fdot2(h, U0.p[j], y0, false);
                y1 = __builtin_amdgcn_fdot2(h, U1.p[j], y1, false);
                y2 = __builtin_amdgcn_fdot2(h, U2.p[j], y2, false);
#else
                y0 += (float)h.x * (float)U0.p[j].x + (float)h.y * (float)U0.p[j].y;
                y1 += (float)h.x * (float)U1.p[j].x + (float)h.y * (float)U1.p[j].y;
                y2 += (float)h.x * (float)U2.p[j].x + (float)h.y * (float)U2.p[j].y;
#endif
            }
        }

        if (lane < cnt) {                             // guard sub-wave padding
            int d = 3 * qg;
            out[d + 0] = y0; out[d + 1] = y1; out[d + 2] = y2;
        }
    }
}

// ---------------------------------------------------------------------------
extern "C" void kernel_launch(void* const* d_in, const int* in_sizes, int n_in,
                              void* d_out, int out_size, void* d_ws, size_t ws_size,
                              hipStream_t stream) {
    const float* samples = (const float*)d_in[0];
    const float* W1      = (const float*)d_in[1];
    const float* b1      = (const float*)d_in[2];
    const float* W2      = (const float*)d_in[3];
    const float* b2      = (const float*)d_in[4];
    float* out = (float*)d_out;

    const int N = in_sizes[0] / 2;
    float*    wsAff = (float*)d_ws;
    int*      wsM2  = (int*)((char*)d_ws + WSOFF_M2);
    _Float16* wsMix = (_Float16*)((char*)d_ws + WSOFF_MIX);

    prep_kernel<<<NEXP, 64, 0, stream>>>(W1, b1, W2, b2, wsAff, wsM2, wsMix);

    const int nblocks = (N + SAMP - 1) / SAMP;        // 512 @ N=524288
    fused_moe_kernel<<<nblocks, TPB, LDS_BYTES, stream>>>(
        (const float2*)samples, wsAff, wsM2, wsMix, out, N);
}